// Round 4
// baseline (73259.186 us; speedup 1.0000x reference)
//
#include <hip/hip_runtime.h>
#include <stdint.h>

typedef float f4 __attribute__((ext_vector_type(4)));

// ---------------- workspace layout (bytes) ----------------
#define WS_H    0ull            // h: [4][64][65536] fp32 = 67,108,864
#define WS_T    67108864ull     // t: same
#define WS_WDT  134217728ull    // [10][64ci][18tap][64co] fp32 = 2,949,120
#define WS_W2T  137166848ull    // [10][64ci][9tap][64co] fp32 = 1,474,560
#define WS_W0T  138641408ull    // [6ci][9tap][64co] fp32 = 13,824
#define WS_WFT  138655232ull    // [64ci][9tap][32co] fp32 = 73,728
#define WS_PAR  138728960ull    // fp32 params

// par float offsets
#define S0 0
#define T0 8
#define S1 16
#define T1 656
#define S2 1296
#define T2 1936
#define SF 2576
#define TF 2640
#define MK 2704
#define CB 3332

// output element offsets (pred, pred_f, mask_f, attn, pred_b, mask_b, 1-attn) — FLOAT32
#define O_PRED   0ull
#define O_PREDF  786432ull
#define O_MASKF  1572864ull
#define O_ATTN   8126464ull
#define O_PREDB  8388608ull
#define O_MASKB  9175040ull
#define O_OMA    15728640ull

// ---------------- params ----------------
__global__ void k_prep(const float* g0,const float* b0,const float* m0,const float* v0,
                       const float* g1,const float* b1,const float* m1,const float* v1,
                       const float* g2,const float* b2,const float* m2,const float* v2,
                       const float* gf,const float* bf_,const float* mf,const float* vf,
                       const float* mk,const float* cb, float* par){
  for (int i = threadIdx.x; i < 640; i += 256){
    if (i < 6){ float s = g0[i]/sqrtf(v0[i]+1e-5f); par[S0+i]=s; par[T0+i]=b0[i]-m0[i]*s; }
    { float s = g1[i]/sqrtf(v1[i]+1e-5f); par[S1+i]=s; par[T1+i]=b1[i]-m1[i]*s; }
    { float s = g2[i]/sqrtf(v2[i]+1e-5f); par[S2+i]=s; par[T2+i]=b2[i]-m2[i]*s; }
    if (i < 64){ float s = gf[i]/sqrtf(vf[i]+1e-5f); par[SF+i]=s; par[TF+i]=bf_[i]-mf[i]*s; }
    if (i < 625) par[MK+i] = mk[i];
    if (i < 25)  par[CB+i] = cb[i];
  }
}

// ---------------- weight transform: [ci][tap][co] ----------------
__global__ void k_wx(const float* w11,const float* w12,const float* w2,
                     const float* wf,const float* w0,
                     float* wdt,float* w2t,float* wft,float* w0t){
  int e = blockIdx.x*256 + threadIdx.x;
  if (e < 737280){
    int o = e & 63, r = e >> 6;
    int tap = r % 18; r /= 18;
    int c = r & 63, b = r >> 6;
    wdt[e] = (tap < 9) ? w11[((b*64+o)*64+c)*9 + tap]
                       : w12[((b*64+o)*64+c)*9 + (tap-9)];
  } else if (e < 1105920){
    int e2 = e - 737280;
    int o = e2 & 63, r = e2 >> 6;
    int tap = r % 9; r /= 9;
    int c = r & 63, b = r >> 6;
    w2t[e2] = w2[((b*64+o)*64+c)*9 + tap];
  } else if (e < 1109376){
    int e3 = e - 1105920;
    int o = e3 & 63, r = e3 >> 6;   // r in [0,54)
    int tap = r % 9, c = r / 9;
    w0t[e3] = w0[(o*6+c)*9 + tap];
  } else if (e < 1127808){
    int e4 = e - 1109376;
    int o = e4 & 31, r = e4 >> 5;
    int tap = r % 9, c = r / 9;
    wft[e4] = (o < 25) ? wf[(o*64+c)*9 + tap] : 0.f;
  }
}

// ---------------- conv0: bn0(x) -> 3x3 conv (6->64), NCHW fp32 ----------------
__global__ __launch_bounds__(256) void k_c0(const float* __restrict__ im,
    const float* __restrict__ w0t, const float* __restrict__ par,
    float* __restrict__ h){
  int p = blockIdx.x*256 + threadIdx.x;
  int img = blockIdx.y;
  int y = p >> 8, x = p & 255;
  f4 acc[16];
  #pragma unroll
  for (int q=0;q<16;q++) acc[q] = f4{0.f,0.f,0.f,0.f};
  #pragma unroll 1
  for (int c=0;c<6;c++){
    float sc = par[S0+c], tc = par[T0+c];
    const float* ip = im + (size_t)(img*6+c)*65536;
    #pragma unroll
    for (int tap=0;tap<9;tap++){
      int sy = y + tap/3 - 1, sx = x + tap%3 - 1;
      if ((unsigned)sy < 256u && (unsigned)sx < 256u){
        float v = ip[sy*256+sx]*sc + tc;
        const f4* wp = (const f4*)(w0t + (c*9+tap)*64);
        #pragma unroll
        for (int q=0;q<16;q++) acc[q] += v*wp[q];
      }
    }
  }
  float* hp = h + (size_t)img*64*65536 + p;
  #pragma unroll
  for (int q=0;q<16;q++)
    #pragma unroll
    for (int j=0;j<4;j++) hp[(size_t)(q*4+j)*65536] = acc[q][j];
}

// ---------------- dual conv: t = conv3x3(relu(bn1 h)) + conv3x3_dil2(relu(bn1 h)) ----------------
__global__ __launch_bounds__(256) void k_dual(const float* __restrict__ h,
    float* __restrict__ t, const float* __restrict__ wdt,
    const float* __restrict__ s1, const float* __restrict__ t1){
  int p = blockIdx.x*256 + threadIdx.x;
  int img = blockIdx.y;
  int y = p >> 8, x = p & 255;
  f4 acc[16];
  #pragma unroll
  for (int q=0;q<16;q++) acc[q] = f4{0.f,0.f,0.f,0.f};
  const float* hb = h + (size_t)img*64*65536;
  #pragma unroll 1
  for (int c=0;c<64;c++){
    float sc = s1[c], tc = t1[c];
    const float* ip = hb + (size_t)c*65536;
    const f4* wc = (const f4*)(wdt + (size_t)c*18*64);
    #pragma unroll
    for (int tap=0;tap<18;tap++){
      int dy, dx;
      if (tap < 9){ dy = tap/3 - 1; dx = tap%3 - 1; }
      else { int dd = tap-9; dy = 2*(dd/3 - 1); dx = 2*(dd%3 - 1); }
      int sy = y + dy, sx = x + dx;
      float v = 0.f;
      if ((unsigned)sy < 256u && (unsigned)sx < 256u)
        v = fmaxf(ip[sy*256+sx]*sc + tc, 0.f);
      #pragma unroll
      for (int q=0;q<16;q++) acc[q] += v*wc[tap*16+q];
    }
  }
  float* tp = t + (size_t)img*64*65536 + p;
  #pragma unroll
  for (int q=0;q<16;q++)
    #pragma unroll
    for (int j=0;j<4;j++) tp[(size_t)(q*4+j)*65536] = acc[q][j];
}

// ---------------- w2 conv + residual: h += conv3x3(relu(bn2 t)) ----------------
__global__ __launch_bounds__(256) void k_w2c(const float* __restrict__ t,
    float* __restrict__ h, const float* __restrict__ w2t,
    const float* __restrict__ s2, const float* __restrict__ t2){
  int p = blockIdx.x*256 + threadIdx.x;
  int img = blockIdx.y;
  int y = p >> 8, x = p & 255;
  f4 acc[16];
  #pragma unroll
  for (int q=0;q<16;q++) acc[q] = f4{0.f,0.f,0.f,0.f};
  const float* tb = t + (size_t)img*64*65536;
  #pragma unroll 1
  for (int c=0;c<64;c++){
    float sc = s2[c], tc = t2[c];
    const float* ip = tb + (size_t)c*65536;
    const f4* wc = (const f4*)(w2t + (size_t)c*9*64);
    #pragma unroll
    for (int tap=0;tap<9;tap++){
      int sy = y + tap/3 - 1, sx = x + tap%3 - 1;
      float v = 0.f;
      if ((unsigned)sy < 256u && (unsigned)sx < 256u)
        v = fmaxf(ip[sy*256+sx]*sc + tc, 0.f);
      #pragma unroll
      for (int q=0;q<16;q++) acc[q] += v*wc[tap*16+q];
    }
  }
  float* hp = h + (size_t)img*64*65536 + p;
  #pragma unroll
  for (int q=0;q<16;q++)
    #pragma unroll
    for (int j=0;j<4;j++) hp[(size_t)(q*4+j)*65536] += acc[q][j];
}

// ---------------- final conv + bias + softmax(25) -> masks (fp32, NCHW planar in d_out) ----------------
__global__ __launch_bounds__(256) void k_fin(const float* __restrict__ h,
    const float* __restrict__ wft, const float* __restrict__ par,
    float* __restrict__ dmask){
  int p = blockIdx.x*256 + threadIdx.x;
  int img = blockIdx.y;
  int y = p >> 8, x = p & 255;
  f4 acc[8];
  #pragma unroll
  for (int q=0;q<8;q++) acc[q] = f4{0.f,0.f,0.f,0.f};
  const float* hb = h + (size_t)img*64*65536;
  #pragma unroll 1
  for (int c=0;c<64;c++){
    float sc = par[SF+c], tc = par[TF+c];
    const float* ip = hb + (size_t)c*65536;
    const f4* wc = (const f4*)(wft + (size_t)c*9*32);
    #pragma unroll
    for (int tap=0;tap<9;tap++){
      int sy = y + tap/3 - 1, sx = x + tap%3 - 1;
      float v = 0.f;
      if ((unsigned)sy < 256u && (unsigned)sx < 256u)
        v = fmaxf(ip[sy*256+sx]*sc + tc, 0.f);
      #pragma unroll
      for (int q=0;q<8;q++) acc[q] += v*wc[tap*8+q];
    }
  }
  float lg[25];
  float mx = -3.4e38f;
  #pragma unroll
  for (int o=0;o<25;o++){ lg[o] = acc[o>>2][o&3] + par[CB+o]; mx = fmaxf(mx, lg[o]); }
  float s = 0.f;
  #pragma unroll
  for (int o=0;o<25;o++){ lg[o] = expf(lg[o]-mx); s += lg[o]; }
  float inv = 1.f/s;
  #pragma unroll
  for (int o=0;o<25;o++)
    dmask[(size_t)(img*25+o)*65536 + p] = lg[o]*inv;
}

// ---------------- seg / pred / attn / blend (fp32 in, fp32 out) ----------------
__global__ __launch_bounds__(256) void k_blend(const float* __restrict__ msk,
    const float* __restrict__ imf, const float* __restrict__ imb,
    const float* __restrict__ ones_in, const float* __restrict__ par,
    float* __restrict__ out){
  int pg = blockIdx.x*256 + threadIdx.x;
  int img = pg >> 16, p = pg & 65535;
  int y = p >> 8, x = p & 255;
  float segf = 0.f, segb = 0.f;
  float pf[3] = {0.f,0.f,0.f}, pb[3] = {0.f,0.f,0.f};
  #pragma unroll 1
  for (int u=0; u<5; u++){
    int sy = y - 2 + u;
    if ((unsigned)sy >= 256u) continue;
    #pragma unroll 1
    for (int v=0; v<5; v++){
      int sx = x - 2 + v;
      if ((unsigned)sx >= 256u) continue;
      int sp = sy*256 + sx;
      float sF = 0.f, sB = 0.f;
      #pragma unroll 1
      for (int k=0;k<25;k++){
        float mkv = par[MK + k*25 + u*5 + v];
        sF += mkv * msk[O_MASKF + (size_t)(img*25+k)*65536 + sp];
        sB += mkv * msk[O_MASKB + (size_t)(img*25+k)*65536 + sp];
      }
      float one = ones_in[(size_t)img*65536 + sp];
      segf += one*sF; segb += one*sB;
      #pragma unroll
      for (int c=0;c<3;c++){
        pf[c] += imf[(size_t)(img*6+3+c)*65536 + sp] * sF;
        pb[c] += imb[(size_t)(img*6+3+c)*65536 + sp] * sB;
      }
    }
  }
  float attn = (segf + 1e-5f)/(segf + segb + 2e-5f);
  float na = 1.f - attn;
  #pragma unroll
  for (int c=0;c<3;c++){
    size_t off = (size_t)(img*3+c)*65536 + p;
    out[O_PRED  + off] = attn*pf[c] + na*pb[c];
    out[O_PREDF + off] = pf[c];
    out[O_PREDB + off] = pb[c];
  }
  size_t oa = (size_t)img*65536 + p;
  out[O_ATTN + oa] = attn;
  out[O_OMA  + oa] = na;
}

// ---------------- launch ----------------
extern "C" void kernel_launch(void* const* d_in, const int* in_sizes, int n_in,
                              void* d_out, int out_size, void* d_ws, size_t ws_size,
                              hipStream_t stream){
  (void)in_sizes; (void)n_in; (void)out_size; (void)ws_size;
  char* ws = (char*)d_ws;
  float* h   = (float*)(ws + WS_H);
  float* t   = (float*)(ws + WS_T);
  float* wdt = (float*)(ws + WS_WDT);
  float* w2t = (float*)(ws + WS_W2T);
  float* w0t = (float*)(ws + WS_W0T);
  float* wft = (float*)(ws + WS_WFT);
  float* par = (float*)(ws + WS_PAR);
  float* out = (float*)d_out;

  k_prep<<<1,256,0,stream>>>((const float*)d_in[4],(const float*)d_in[5],(const float*)d_in[6],(const float*)d_in[7],
                             (const float*)d_in[9],(const float*)d_in[10],(const float*)d_in[11],(const float*)d_in[12],
                             (const float*)d_in[15],(const float*)d_in[16],(const float*)d_in[17],(const float*)d_in[18],
                             (const float*)d_in[20],(const float*)d_in[21],(const float*)d_in[22],(const float*)d_in[23],
                             (const float*)d_in[3],(const float*)d_in[25], par);
  k_wx<<<4406,256,0,stream>>>((const float*)d_in[13],(const float*)d_in[14],(const float*)d_in[19],
                              (const float*)d_in[24],(const float*)d_in[8],
                              wdt, w2t, wft, w0t);

  dim3 g(256,4,1);
  for (int dir=0; dir<2; dir++){
    const float* im = (const float*)d_in[dir];
    float* dmask = out + (dir ? O_MASKB : O_MASKF);
    k_c0<<<g,256,0,stream>>>(im, w0t, par, h);
    for (int b=0;b<10;b++){
      k_dual<<<g,256,0,stream>>>(h, t, wdt + (size_t)b*73728,
                                 par + S1 + b*64, par + T1 + b*64);
      k_w2c<<<g,256,0,stream>>>(t, h, w2t + (size_t)b*36864,
                                par + S2 + b*64, par + T2 + b*64);
    }
    k_fin<<<g,256,0,stream>>>(h, wft, par, dmask);
  }
  k_blend<<<1024,256,0,stream>>>(out, (const float*)d_in[0], (const float*)d_in[1],
                                 (const float*)d_in[2], par, out);
}

// Round 5
// 15560.646 us; speedup vs baseline: 4.7080x; 4.7080x over previous
//
#include <hip/hip_runtime.h>
#include <stdint.h>

typedef float f4 __attribute__((ext_vector_type(4)));

// ---------------- workspace layout (bytes) ----------------
#define WS_H    0ull            // h: [4][64][65536] fp32 = 67,108,864
#define WS_T    67108864ull     // t: same
#define WS_WDT  134217728ull    // [10][64ci][18tap][64co] fp32
#define WS_W2T  137166848ull    // [10][64ci][9tap][64co] fp32
#define WS_W0T  138641408ull    // [6ci][9tap][64co] fp32
#define WS_WFT  138655232ull    // [64ci][9tap][32co] fp32
#define WS_PAR  138728960ull    // fp32 params

// par float offsets
#define S0 0
#define T0 8
#define S1 16
#define T1 656
#define S2 1296
#define T2 1936
#define SF 2576
#define TF 2640
#define MK 2704
#define CB 3332

// output element offsets (pred, pred_f, mask_f, attn, pred_b, mask_b, 1-attn) — FLOAT32
#define O_PRED   0ull
#define O_PREDF  786432ull
#define O_MASKF  1572864ull
#define O_ATTN   8126464ull
#define O_PREDB  8388608ull
#define O_MASKB  9175040ull
#define O_OMA    15728640ull

// ---------------- params ----------------
__global__ void k_prep(const float* g0,const float* b0,const float* m0,const float* v0,
                       const float* g1,const float* b1,const float* m1,const float* v1,
                       const float* g2,const float* b2,const float* m2,const float* v2,
                       const float* gf,const float* bf_,const float* mf,const float* vf,
                       const float* mk,const float* cb, float* par){
  for (int i = threadIdx.x; i < 640; i += 256){
    if (i < 6){ float s = g0[i]/sqrtf(v0[i]+1e-5f); par[S0+i]=s; par[T0+i]=b0[i]-m0[i]*s; }
    { float s = g1[i]/sqrtf(v1[i]+1e-5f); par[S1+i]=s; par[T1+i]=b1[i]-m1[i]*s; }
    { float s = g2[i]/sqrtf(v2[i]+1e-5f); par[S2+i]=s; par[T2+i]=b2[i]-m2[i]*s; }
    if (i < 64){ float s = gf[i]/sqrtf(vf[i]+1e-5f); par[SF+i]=s; par[TF+i]=bf_[i]-mf[i]*s; }
    if (i < 625) par[MK+i] = mk[i];
    if (i < 25)  par[CB+i] = cb[i];
  }
}

// ---------------- weight transform: [ci][tap][co] ----------------
__global__ void k_wx(const float* w11,const float* w12,const float* w2,
                     const float* wf,const float* w0,
                     float* wdt,float* w2t,float* wft,float* w0t){
  int e = blockIdx.x*256 + threadIdx.x;
  if (e < 737280){
    int o = e & 63, r = e >> 6;
    int tap = r % 18; r /= 18;
    int c = r & 63, b = r >> 6;
    wdt[e] = (tap < 9) ? w11[((b*64+o)*64+c)*9 + tap]
                       : w12[((b*64+o)*64+c)*9 + (tap-9)];
  } else if (e < 1105920){
    int e2 = e - 737280;
    int o = e2 & 63, r = e2 >> 6;
    int tap = r % 9; r /= 9;
    int c = r & 63, b = r >> 6;
    w2t[e2] = w2[((b*64+o)*64+c)*9 + tap];
  } else if (e < 1109376){
    int e3 = e - 1105920;
    int o = e3 & 63, r = e3 >> 6;
    int tap = r % 9, c = r / 9;
    w0t[e3] = w0[(o*6+c)*9 + tap];
  } else if (e < 1127808){
    int e4 = e - 1109376;
    int o = e4 & 31, r = e4 >> 5;
    int tap = r % 9, c = r / 9;
    wft[e4] = (o < 25) ? wf[(o*64+c)*9 + tap] : 0.f;
  }
}

// ---------------- unified tiled conv ----------------
// Block 256 = 4 waves. Output tile 16x8 px, 64 co. Wave w: co [w*16, w*16+16).
// Each lane: 2 px (row, row+4). Input+weights staged in LDS, 4-channel chunks.
// OUTMODE 0: store; 1: residual add into outb.
template<int NTAPS,int TAPSET,int OUTMODE,int RELU>
__global__ __launch_bounds__(256) void k_conv(
    const float* __restrict__ in, float* __restrict__ outb,
    const float* __restrict__ wt, const float* __restrict__ sc_,
    const float* __restrict__ tc_, int nci){
  __shared__ float lin[4*12*20];
  __shared__ float lw[4*NTAPS*64];
  __shared__ float lsc[64], ltc[64];
  const int t = threadIdx.x;
  const int img = blockIdx.z;
  const int ox = blockIdx.x*16, oy = blockIdx.y*8;
  if (t < 64 && t < nci){ lsc[t] = sc_[t]; ltc[t] = tc_[t]; }
  const int wv = t>>6, lane = t&63;
  const int row = lane>>4, col = lane&15;
  const int co0 = wv*16;
  const int pb0 = (row+2)*20 + col + 2;
  const int pb1 = pb0 + 80;
  f4 a0[4], a1[4];
  #pragma unroll
  for (int q=0;q<4;q++){ a0[q] = f4{0.f,0.f,0.f,0.f}; a1[q] = f4{0.f,0.f,0.f,0.f}; }

  #pragma unroll 1
  for (int c0=0; c0<nci; c0+=4){
    const int cc = (nci - c0 < 4) ? (nci - c0) : 4;
    __syncthreads();
    // stage input tile (bn+optional relu fused; OOB = 0)
    for (int idx=t; idx<cc*240; idx+=256){
      int c = idx/240, rr = (idx/20)%12, xx = idx%20;
      int gy = oy + rr - 2, gx = ox + xx - 2;
      float v = 0.f;
      if ((unsigned)gy < 256u && (unsigned)gx < 256u){
        v = in[(size_t)(img*nci + c0 + c)*65536 + gy*256 + gx]*lsc[c0+c] + ltc[c0+c];
        if (RELU) v = fmaxf(v, 0.f);
      }
      lin[idx] = v;
    }
    // stage weights (contiguous [ci][tap][co] slab)
    {
      const f4* ws4 = (const f4*)(wt + (size_t)c0*NTAPS*64);
      f4* lw4 = (f4*)lw;
      for (int idx=t; idx<cc*NTAPS*16; idx+=256) lw4[idx] = ws4[idx];
    }
    __syncthreads();
    #pragma unroll 1
    for (int c=0; c<cc; c++){
      const float* lpc = lin + c*240;
      const float* lwc = lw + c*NTAPS*64 + co0;
      #pragma unroll
      for (int tap=0; tap<NTAPS; tap++){
        int dy, dx;
        if (TAPSET==0){
          if (tap < 9){ dy = tap/3 - 1; dx = tap%3 - 1; }
          else { int dd = tap-9; dy = 2*(dd/3 - 1); dx = 2*(dd%3 - 1); }
        } else { dy = tap/3 - 1; dx = tap%3 - 1; }
        float v0 = lpc[pb0 + dy*20 + dx];
        float v1 = lpc[pb1 + dy*20 + dx];
        const f4* wp = (const f4*)(lwc + tap*64);
        #pragma unroll
        for (int q=0;q<4;q++){
          f4 w = wp[q];
          a0[q] += v0*w;
          a1[q] += v1*w;
        }
      }
    }
  }

  size_t p0 = (size_t)((oy+row)*256 + ox + col);
  size_t base = (size_t)(img*64 + co0)*65536;
  if (OUTMODE==0){
    #pragma unroll
    for (int q=0;q<4;q++)
      #pragma unroll
      for (int j=0;j<4;j++){
        outb[base + (size_t)(q*4+j)*65536 + p0]        = a0[q][j];
        outb[base + (size_t)(q*4+j)*65536 + p0 + 1024] = a1[q][j];
      }
  } else {
    #pragma unroll
    for (int q=0;q<4;q++)
      #pragma unroll
      for (int j=0;j<4;j++){
        size_t o0 = base + (size_t)(q*4+j)*65536 + p0;
        outb[o0]        += a0[q][j];
        outb[o0 + 1024] += a1[q][j];
      }
  }
}

// ---------------- final conv + softmax(25): 1 px/thread, 32 co, tile 16x16 ----------------
__global__ __launch_bounds__(256) void k_fin2(const float* __restrict__ in,
    const float* __restrict__ wft, const float* __restrict__ par,
    float* __restrict__ dmask){
  __shared__ float lin[4*20*20];
  __shared__ float lw[4*9*32];
  __shared__ float lsc[64], ltc[64];
  const int t = threadIdx.x;
  const int img = blockIdx.z;
  const int ox = blockIdx.x*16, oy = blockIdx.y*16;
  if (t < 64){ lsc[t] = par[SF+t]; ltc[t] = par[TF+t]; }
  const int row = t>>4, col = t&15;
  const int pb = (row+2)*20 + col + 2;
  f4 a[8];
  #pragma unroll
  for (int q=0;q<8;q++) a[q] = f4{0.f,0.f,0.f,0.f};

  #pragma unroll 1
  for (int c0=0; c0<64; c0+=4){
    __syncthreads();
    for (int idx=t; idx<4*400; idx+=256){
      int c = idx/400, rr = (idx/20)%20, xx = idx%20;
      int gy = oy + rr - 2, gx = ox + xx - 2;
      float v = 0.f;
      if ((unsigned)gy < 256u && (unsigned)gx < 256u)
        v = fmaxf(in[(size_t)(img*64 + c0 + c)*65536 + gy*256 + gx]*lsc[c0+c] + ltc[c0+c], 0.f);
      lin[idx] = v;
    }
    {
      const f4* ws4 = (const f4*)(wft + (size_t)c0*288);
      f4* lw4 = (f4*)lw;
      for (int idx=t; idx<288; idx+=256) lw4[idx] = ws4[idx];
    }
    __syncthreads();
    #pragma unroll 1
    for (int c=0; c<4; c++){
      const float* lpc = lin + c*400;
      const float* lwc = lw + c*288;
      #pragma unroll
      for (int tap=0; tap<9; tap++){
        int dy = tap/3 - 1, dx = tap%3 - 1;
        float v = lpc[pb + dy*20 + dx];
        const f4* wp = (const f4*)(lwc + tap*32);
        #pragma unroll
        for (int q=0;q<8;q++) a[q] += v*wp[q];
      }
    }
  }

  float lg[25];
  float mx = -3.4e38f;
  #pragma unroll
  for (int o=0;o<25;o++){ lg[o] = a[o>>2][o&3] + par[CB+o]; mx = fmaxf(mx, lg[o]); }
  float s = 0.f;
  #pragma unroll
  for (int o=0;o<25;o++){ lg[o] = expf(lg[o]-mx); s += lg[o]; }
  float inv = 1.f/s;
  size_t p0 = (size_t)((oy+row)*256 + ox + col);
  #pragma unroll
  for (int o=0;o<25;o++)
    dmask[(size_t)(img*25+o)*65536 + p0] = lg[o]*inv;
}

// ---------------- seg / pred / attn / blend ----------------
__global__ __launch_bounds__(256) void k_blend(const float* __restrict__ msk,
    const float* __restrict__ imf, const float* __restrict__ imb,
    const float* __restrict__ ones_in, const float* __restrict__ par,
    float* __restrict__ out){
  int pg = blockIdx.x*256 + threadIdx.x;
  int img = pg >> 16, p = pg & 65535;
  int y = p >> 8, x = p & 255;
  float segf = 0.f, segb = 0.f;
  float pf[3] = {0.f,0.f,0.f}, pb[3] = {0.f,0.f,0.f};
  #pragma unroll 1
  for (int u=0; u<5; u++){
    int sy = y - 2 + u;
    if ((unsigned)sy >= 256u) continue;
    #pragma unroll 1
    for (int v=0; v<5; v++){
      int sx = x - 2 + v;
      if ((unsigned)sx >= 256u) continue;
      int sp = sy*256 + sx;
      float sF = 0.f, sB = 0.f;
      #pragma unroll 1
      for (int k=0;k<25;k++){
        float mkv = par[MK + k*25 + u*5 + v];
        sF += mkv * msk[O_MASKF + (size_t)(img*25+k)*65536 + sp];
        sB += mkv * msk[O_MASKB + (size_t)(img*25+k)*65536 + sp];
      }
      float one = ones_in[(size_t)img*65536 + sp];
      segf += one*sF; segb += one*sB;
      #pragma unroll
      for (int c=0;c<3;c++){
        pf[c] += imf[(size_t)(img*6+3+c)*65536 + sp] * sF;
        pb[c] += imb[(size_t)(img*6+3+c)*65536 + sp] * sB;
      }
    }
  }
  float attn = (segf + 1e-5f)/(segf + segb + 2e-5f);
  float na = 1.f - attn;
  #pragma unroll
  for (int c=0;c<3;c++){
    size_t off = (size_t)(img*3+c)*65536 + p;
    out[O_PRED  + off] = attn*pf[c] + na*pb[c];
    out[O_PREDF + off] = pf[c];
    out[O_PREDB + off] = pb[c];
  }
  size_t oa = (size_t)img*65536 + p;
  out[O_ATTN + oa] = attn;
  out[O_OMA  + oa] = na;
}

// ---------------- launch ----------------
extern "C" void kernel_launch(void* const* d_in, const int* in_sizes, int n_in,
                              void* d_out, int out_size, void* d_ws, size_t ws_size,
                              hipStream_t stream){
  (void)in_sizes; (void)n_in; (void)out_size; (void)ws_size;
  char* ws = (char*)d_ws;
  float* h   = (float*)(ws + WS_H);
  float* tb  = (float*)(ws + WS_T);
  float* wdt = (float*)(ws + WS_WDT);
  float* w2t = (float*)(ws + WS_W2T);
  float* w0t = (float*)(ws + WS_W0T);
  float* wft = (float*)(ws + WS_WFT);
  float* par = (float*)(ws + WS_PAR);
  float* out = (float*)d_out;

  k_prep<<<1,256,0,stream>>>((const float*)d_in[4],(const float*)d_in[5],(const float*)d_in[6],(const float*)d_in[7],
                             (const float*)d_in[9],(const float*)d_in[10],(const float*)d_in[11],(const float*)d_in[12],
                             (const float*)d_in[15],(const float*)d_in[16],(const float*)d_in[17],(const float*)d_in[18],
                             (const float*)d_in[20],(const float*)d_in[21],(const float*)d_in[22],(const float*)d_in[23],
                             (const float*)d_in[3],(const float*)d_in[25], par);
  k_wx<<<4406,256,0,stream>>>((const float*)d_in[13],(const float*)d_in[14],(const float*)d_in[19],
                              (const float*)d_in[24],(const float*)d_in[8],
                              wdt, w2t, wft, w0t);

  dim3 gm(16,32,4);   // 16x8 tiles
  dim3 gf(16,16,4);   // 16x16 tiles
  for (int dir=0; dir<2; dir++){
    const float* im = (const float*)d_in[dir];
    float* dmask = out + (dir ? O_MASKB : O_MASKF);
    k_conv<9,1,0,0><<<gm,256,0,stream>>>(im, h, w0t, par+S0, par+T0, 6);
    for (int b=0;b<10;b++){
      k_conv<18,0,0,1><<<gm,256,0,stream>>>(h, tb, wdt + (size_t)b*73728,
                                            par + S1 + b*64, par + T1 + b*64, 64);
      k_conv<9,1,1,1><<<gm,256,0,stream>>>(tb, h, w2t + (size_t)b*36864,
                                           par + S2 + b*64, par + T2 + b*64, 64);
    }
    k_fin2<<<gf,256,0,stream>>>(h, wft, par, dmask);
  }
  k_blend<<<1024,256,0,stream>>>(out, (const float*)d_in[0], (const float*)d_in[1],
                                 (const float*)d_in[2], par, out);
}

// Round 6
// 4094.888 us; speedup vs baseline: 17.8904x; 3.8000x over previous
//
#include <hip/hip_runtime.h>
#include <stdint.h>

typedef unsigned short u16;
typedef float f4 __attribute__((ext_vector_type(4)));
typedef short s8v __attribute__((ext_vector_type(8)));

static __device__ __forceinline__ float bf2f(u16 u){ return __uint_as_float(((unsigned)u)<<16); }
static __device__ __forceinline__ u16 f2bf(float f){
  unsigned u = __float_as_uint(f);
  unsigned r = u + 0x7fffu + ((u>>16)&1u);
  return (u16)(r>>16);
}

// ---------------- workspace layout (bytes) ----------------
#define WS_H    0ull            // h: [4][64][65536] fp32 = 67,108,864
#define WS_T    67108864ull     // t: same
#define WS_WDH  134217728ull    // dual hi frags: 10*73728 bf16 = 1,474,560 B
#define WS_WDL  135692288ull    // dual lo frags
#define WS_W2H  137166848ull    // w2 hi frags: 10*36864 bf16 = 737,280 B
#define WS_W2L  137904128ull
#define WS_W0T  138641408ull    // [6ci][9tap][64co] fp32 = 13,824
#define WS_WFT  138655232ull    // [64ci][9tap][32co] fp32 = 73,728
#define WS_PAR  138728960ull    // fp32 params

// par float offsets
#define S0 0
#define T0 8
#define S1 16
#define T1 656
#define S2 1296
#define T2 1936
#define SF 2576
#define TF 2640
#define MK 2704
#define CB 3332

// output element offsets (pred, pred_f, mask_f, attn, pred_b, mask_b, 1-attn) — FLOAT32
#define O_PRED   0ull
#define O_PREDF  786432ull
#define O_MASKF  1572864ull
#define O_ATTN   8126464ull
#define O_PREDB  8388608ull
#define O_MASKB  9175040ull
#define O_OMA    15728640ull

// ---------------- params ----------------
__global__ void k_prep(const float* g0,const float* b0,const float* m0,const float* v0,
                       const float* g1,const float* b1,const float* m1,const float* v1,
                       const float* g2,const float* b2,const float* m2,const float* v2,
                       const float* gf,const float* bf_,const float* mf,const float* vf,
                       const float* mk,const float* cb, float* par){
  for (int i = threadIdx.x; i < 640; i += 256){
    if (i < 6){ float s = g0[i]/sqrtf(v0[i]+1e-5f); par[S0+i]=s; par[T0+i]=b0[i]-m0[i]*s; }
    { float s = g1[i]/sqrtf(v1[i]+1e-5f); par[S1+i]=s; par[T1+i]=b1[i]-m1[i]*s; }
    { float s = g2[i]/sqrtf(v2[i]+1e-5f); par[S2+i]=s; par[T2+i]=b2[i]-m2[i]*s; }
    if (i < 64){ float s = gf[i]/sqrtf(vf[i]+1e-5f); par[SF+i]=s; par[TF+i]=bf_[i]-mf[i]*s; }
    if (i < 625) par[MK+i] = mk[i];
    if (i < 25)  par[CB+i] = cb[i];
  }
}

// ---------------- small weights: [ci][tap][co] fp32 (conv0, fin) ----------------
__global__ void k_wx2(const float* wf,const float* w0, float* wft, float* w0t){
  int e = blockIdx.x*256 + threadIdx.x;
  if (e < 3456){
    int o = e & 63, r = e >> 6;
    int tap = r % 9, c = r / 9;
    w0t[e] = w0[(o*6+c)*9 + tap];
  } else if (e < 3456 + 18432){
    int e4 = e - 3456;
    int o = e4 & 31, r = e4 >> 5;
    int tap = r % 9, c = r / 9;
    wft[e4] = (o < 25) ? wf[(o*64+c)*9 + tap] : 0.f;
  }
}

// ---------------- MFMA weight fragment streams (hi/lo bf16x2 split) ----------------
// Layout: frag[tf][cog][lane][8], tf = h*NT + tap, h = ci-half.
// Element (tf,cog,l,j): co = cog*16 + (l&15); ci = h*32 + ((l>>4)&3)*8 + j.
__global__ void k_wxm(const float* w11, const float* w12, const float* w2,
                      u16* wdH, u16* wdL, u16* w2H, u16* w2L){
  int e = blockIdx.x*256 + threadIdx.x;
  if (e < 737280){
    int b = e / 73728, f = e % 73728;
    int j = f & 7, l = (f>>3) & 63, cog = (f>>9) & 3, tf = f >> 11;  // tf in [0,36)
    int tap = tf % 18, h = tf / 18;
    int co = cog*16 + (l & 15);
    int ci = h*32 + ((l>>4)&3)*8 + j;
    float w = (tap < 9) ? w11[((b*64+co)*64+ci)*9 + tap]
                        : w12[((b*64+co)*64+ci)*9 + (tap-9)];
    u16 hi = f2bf(w);
    wdH[e] = hi; wdL[e] = f2bf(w - bf2f(hi));
  } else if (e < 1105920){
    int e2 = e - 737280;
    int b = e2 / 36864, f = e2 % 36864;
    int j = f & 7, l = (f>>3) & 63, cog = (f>>9) & 3, tf = f >> 11;  // tf in [0,18)
    int tap = tf % 9, h = tf / 9;
    int co = cog*16 + (l & 15);
    int ci = h*32 + ((l>>4)&3)*8 + j;
    float w = w2[((b*64+co)*64+ci)*9 + tap];
    u16 hi = f2bf(w);
    w2H[e2] = hi; w2L[e2] = f2bf(w - bf2f(hi));
  }
}

// ---------------- MFMA conv: relu(bn(in)) -> tap-GEMM, bf16x2 (3-MFMA) ----------------
// Block 256 = 4 waves. Out tile 8x32 px, 64 co. Wave w: wc=w&1 -> co [wc*32,+32),
// wp=w>>1 -> rows [wp*4,+4) (8 px-tiles of 16). K processed per ci-half (32ch staged).
// OUTMODE 0: store to outb; 1: outb += acc (residual).
template<int NT,int TAPSET,int OUTMODE>
__global__ __launch_bounds__(256,2) void k_mconv(
    const float* __restrict__ in, float* __restrict__ outb,
    const u16* __restrict__ wH, const u16* __restrict__ wL,
    const float* __restrict__ sc_, const float* __restrict__ tc_){
  __shared__ __align__(16) u16 ldsH[12*36*32];
  __shared__ __align__(16) u16 ldsL[12*36*32];
  __shared__ float lsc[64], ltc[64];
  const int t = threadIdx.x;
  if (t < 64){ lsc[t] = sc_[t]; ltc[t] = tc_[t]; }
  const int img = blockIdx.z, ox = blockIdx.x*32, oy = blockIdx.y*8;
  const int lane = t & 63, wv = t >> 6;
  const int wc = wv & 1, wp = wv >> 1;
  const int P = lane & 15, lhi = lane >> 4;
  // per-lane B-frag base (bytes); rows biased by -2 so all tap offsets are >=0
  const int pbase = (wp*4*36 + P)*64 + lhi*16;
  f4 acc[2][8];
  #pragma unroll
  for (int c2=0;c2<2;c2++)
    #pragma unroll
    for (int n=0;n<8;n++) acc[c2][n] = f4{0.f,0.f,0.f,0.f};
  const s8v* wH8 = (const s8v*)wH;
  const s8v* wL8 = (const s8v*)wL;

  #pragma unroll 1
  for (int h = 0; h < 2; ++h){
    __syncthreads();
    // stage half h: 432 halo px x 32 ci, bn+relu+split hi/lo
    for (int idx = t; idx < 1728; idx += 256){
      int oct = idx / 432, px = idx % 432;
      int pr = px / 36, pc = px % 36;
      int gy = oy + pr - 2, gx = ox + pc - 2;
      int cb = h*32 + oct*8;
      s8v vh = {0,0,0,0,0,0,0,0}, vl = {0,0,0,0,0,0,0,0};
      if ((unsigned)gy < 256u && (unsigned)gx < 256u){
        const float* ip = in + (((size_t)(img*64 + cb))<<16) + gy*256 + gx;
        #pragma unroll
        for (int k=0;k<8;k++){
          float v = fmaxf(ip[(size_t)k<<16]*lsc[cb+k] + ltc[cb+k], 0.f);
          u16 hi = f2bf(v);
          vh[k] = (short)hi;
          vl[k] = (short)f2bf(v - bf2f(hi));
        }
      }
      int ad = px*64 + oct*16;
      *(s8v*)((char*)ldsH + ad) = vh;
      *(s8v*)((char*)ldsL + ad) = vl;
    }
    __syncthreads();
    #pragma unroll
    for (int tap = 0; tap < NT; ++tap){
      int dy, dx;
      if (TAPSET==0){
        if (tap < 9){ dy = tap/3 - 1; dx = tap%3 - 1; }
        else { int dd = tap-9; dy = 2*(dd/3 - 1); dx = 2*(dd%3 - 1); }
      } else { dy = tap/3 - 1; dx = tap%3 - 1; }
      const int tf = h*NT + tap;
      s8v ah0 = wH8[(size_t)((tf*4 + wc*2 + 0)*64 + lane)];
      s8v al0 = wL8[(size_t)((tf*4 + wc*2 + 0)*64 + lane)];
      s8v ah1 = wH8[(size_t)((tf*4 + wc*2 + 1)*64 + lane)];
      s8v al1 = wL8[(size_t)((tf*4 + wc*2 + 1)*64 + lane)];
      #pragma unroll
      for (int n = 0; n < 8; ++n){
        const int off = (((n>>1) + dy + 2)*36 + (n&1)*16 + dx + 2)*64;
        s8v xh = *(const s8v*)((const char*)ldsH + pbase + off);
        s8v xl = *(const s8v*)((const char*)ldsL + pbase + off);
        acc[0][n] = __builtin_amdgcn_mfma_f32_16x16x32_bf16(ah0, xh, acc[0][n], 0,0,0);
        acc[1][n] = __builtin_amdgcn_mfma_f32_16x16x32_bf16(ah1, xh, acc[1][n], 0,0,0);
        acc[0][n] = __builtin_amdgcn_mfma_f32_16x16x32_bf16(al0, xh, acc[0][n], 0,0,0);
        acc[1][n] = __builtin_amdgcn_mfma_f32_16x16x32_bf16(al1, xh, acc[1][n], 0,0,0);
        acc[0][n] = __builtin_amdgcn_mfma_f32_16x16x32_bf16(ah0, xl, acc[0][n], 0,0,0);
        acc[1][n] = __builtin_amdgcn_mfma_f32_16x16x32_bf16(ah1, xl, acc[1][n], 0,0,0);
      }
    }
  }

  // write out: D col (lane&15) = px, D row ((lane>>4)*4+j) = co-within-16
  #pragma unroll
  for (int c2=0;c2<2;c2++){
    #pragma unroll
    for (int n=0;n<8;n++){
      int y = oy + wp*4 + (n>>1);
      int x = ox + (n&1)*16 + P;
      #pragma unroll
      for (int j=0;j<4;j++){
        int co = (wc*2 + c2)*16 + lhi*4 + j;
        size_t o = (((size_t)(img*64 + co))<<16) + (size_t)(y*256 + x);
        if (OUTMODE==0) outb[o] = acc[c2][n][j];
        else            outb[o] += acc[c2][n][j];
      }
    }
  }
}

// ---------------- conv0 (VALU, 6ci): tile 16x8, LDS staged ----------------
template<int NTAPS,int TAPSET,int OUTMODE,int RELU>
__global__ __launch_bounds__(256) void k_conv(
    const float* __restrict__ in, float* __restrict__ outb,
    const float* __restrict__ wt, const float* __restrict__ sc_,
    const float* __restrict__ tc_, int nci){
  __shared__ float lin[4*12*20];
  __shared__ float lw[4*NTAPS*64];
  __shared__ float lsc[64], ltc[64];
  const int t = threadIdx.x;
  const int img = blockIdx.z;
  const int ox = blockIdx.x*16, oy = blockIdx.y*8;
  if (t < 64 && t < nci){ lsc[t] = sc_[t]; ltc[t] = tc_[t]; }
  const int wv = t>>6, lane = t&63;
  const int row = lane>>4, col = lane&15;
  const int co0 = wv*16;
  const int pb0 = (row+2)*20 + col + 2;
  const int pb1 = pb0 + 80;
  f4 a0[4], a1[4];
  #pragma unroll
  for (int q=0;q<4;q++){ a0[q] = f4{0.f,0.f,0.f,0.f}; a1[q] = f4{0.f,0.f,0.f,0.f}; }

  #pragma unroll 1
  for (int c0=0; c0<nci; c0+=4){
    const int cc = (nci - c0 < 4) ? (nci - c0) : 4;
    __syncthreads();
    for (int idx=t; idx<cc*240; idx+=256){
      int c = idx/240, rr = (idx/20)%12, xx = idx%20;
      int gy = oy + rr - 2, gx = ox + xx - 2;
      float v = 0.f;
      if ((unsigned)gy < 256u && (unsigned)gx < 256u){
        v = in[(size_t)(img*nci + c0 + c)*65536 + gy*256 + gx]*lsc[c0+c] + ltc[c0+c];
        if (RELU) v = fmaxf(v, 0.f);
      }
      lin[idx] = v;
    }
    {
      const f4* ws4 = (const f4*)(wt + (size_t)c0*NTAPS*64);
      f4* lw4 = (f4*)lw;
      for (int idx=t; idx<cc*NTAPS*16; idx+=256) lw4[idx] = ws4[idx];
    }
    __syncthreads();
    #pragma unroll 1
    for (int c=0; c<cc; c++){
      const float* lpc = lin + c*240;
      const float* lwc = lw + c*NTAPS*64 + co0;
      #pragma unroll
      for (int tap=0; tap<NTAPS; tap++){
        int dy, dx;
        if (TAPSET==0){
          if (tap < 9){ dy = tap/3 - 1; dx = tap%3 - 1; }
          else      { dy = 2*((tap-9)/3-1); dx = 2*((tap-9)%3-1); }
        } else { dy = tap/3 - 1; dx = tap%3 - 1; }
        float v0 = lpc[pb0 + dy*20 + dx];
        float v1 = lpc[pb1 + dy*20 + dx];
        const f4* wp = (const f4*)(lwc + tap*64);
        #pragma unroll
        for (int q=0;q<4;q++){
          f4 w = wp[q];
          a0[q] += v0*w;
          a1[q] += v1*w;
        }
      }
    }
  }

  size_t p0 = (size_t)((oy+row)*256 + ox + col);
  size_t base = (size_t)(img*64 + co0)*65536;
  if (OUTMODE==0){
    #pragma unroll
    for (int q=0;q<4;q++)
      #pragma unroll
      for (int j=0;j<4;j++){
        outb[base + (size_t)(q*4+j)*65536 + p0]        = a0[q][j];
        outb[base + (size_t)(q*4+j)*65536 + p0 + 1024] = a1[q][j];
      }
  } else {
    #pragma unroll
    for (int q=0;q<4;q++)
      #pragma unroll
      for (int j=0;j<4;j++){
        size_t o0 = base + (size_t)(q*4+j)*65536 + p0;
        outb[o0]        += a0[q][j];
        outb[o0 + 1024] += a1[q][j];
      }
  }
}

// ---------------- final conv + softmax(25) ----------------
__global__ __launch_bounds__(256) void k_fin2(const float* __restrict__ in,
    const float* __restrict__ wft, const float* __restrict__ par,
    float* __restrict__ dmask){
  __shared__ float lin[4*20*20];
  __shared__ float lw[4*9*32];
  __shared__ float lsc[64], ltc[64];
  const int t = threadIdx.x;
  const int img = blockIdx.z;
  const int ox = blockIdx.x*16, oy = blockIdx.y*16;
  if (t < 64){ lsc[t] = par[SF+t]; ltc[t] = par[TF+t]; }
  const int row = t>>4, col = t&15;
  const int pb = (row+2)*20 + col + 2;
  f4 a[8];
  #pragma unroll
  for (int q=0;q<8;q++) a[q] = f4{0.f,0.f,0.f,0.f};

  #pragma unroll 1
  for (int c0=0; c0<64; c0+=4){
    __syncthreads();
    for (int idx=t; idx<4*400; idx+=256){
      int c = idx/400, rr = (idx/20)%20, xx = idx%20;
      int gy = oy + rr - 2, gx = ox + xx - 2;
      float v = 0.f;
      if ((unsigned)gy < 256u && (unsigned)gx < 256u)
        v = fmaxf(in[(size_t)(img*64 + c0 + c)*65536 + gy*256 + gx]*lsc[c0+c] + ltc[c0+c], 0.f);
      lin[idx] = v;
    }
    {
      const f4* ws4 = (const f4*)(wft + (size_t)c0*288);
      f4* lw4 = (f4*)lw;
      for (int idx=t; idx<288; idx+=256) lw4[idx] = ws4[idx];
    }
    __syncthreads();
    #pragma unroll 1
    for (int c=0; c<4; c++){
      const float* lpc = lin + c*400;
      const float* lwc = lw + c*288;
      #pragma unroll
      for (int tap=0; tap<9; tap++){
        int dy = tap/3 - 1, dx = tap%3 - 1;
        float v = lpc[pb + dy*20 + dx];
        const f4* wp = (const f4*)(lwc + tap*32);
        #pragma unroll
        for (int q=0;q<8;q++) a[q] += v*wp[q];
      }
    }
  }

  float lg[25];
  float mx = -3.4e38f;
  #pragma unroll
  for (int o=0;o<25;o++){ lg[o] = a[o>>2][o&3] + par[CB+o]; mx = fmaxf(mx, lg[o]); }
  float s = 0.f;
  #pragma unroll
  for (int o=0;o<25;o++){ lg[o] = expf(lg[o]-mx); s += lg[o]; }
  float inv = 1.f/s;
  size_t p0 = (size_t)((oy+row)*256 + ox + col);
  #pragma unroll
  for (int o=0;o<25;o++)
    dmask[(size_t)(img*25+o)*65536 + p0] = lg[o]*inv;
}

// ---------------- seg / pred / attn / blend ----------------
__global__ __launch_bounds__(256) void k_blend(const float* __restrict__ msk,
    const float* __restrict__ imf, const float* __restrict__ imb,
    const float* __restrict__ ones_in, const float* __restrict__ par,
    float* __restrict__ out){
  int pg = blockIdx.x*256 + threadIdx.x;
  int img = pg >> 16, p = pg & 65535;
  int y = p >> 8, x = p & 255;
  float segf = 0.f, segb = 0.f;
  float pf[3] = {0.f,0.f,0.f}, pb[3] = {0.f,0.f,0.f};
  #pragma unroll 1
  for (int u=0; u<5; u++){
    int sy = y - 2 + u;
    if ((unsigned)sy >= 256u) continue;
    #pragma unroll 1
    for (int v=0; v<5; v++){
      int sx = x - 2 + v;
      if ((unsigned)sx >= 256u) continue;
      int sp = sy*256 + sx;
      float sF = 0.f, sB = 0.f;
      #pragma unroll 1
      for (int k=0;k<25;k++){
        float mkv = par[MK + k*25 + u*5 + v];
        sF += mkv * msk[O_MASKF + (size_t)(img*25+k)*65536 + sp];
        sB += mkv * msk[O_MASKB + (size_t)(img*25+k)*65536 + sp];
      }
      float one = ones_in[(size_t)img*65536 + sp];
      segf += one*sF; segb += one*sB;
      #pragma unroll
      for (int c=0;c<3;c++){
        pf[c] += imf[(size_t)(img*6+3+c)*65536 + sp] * sF;
        pb[c] += imb[(size_t)(img*6+3+c)*65536 + sp] * sB;
      }
    }
  }
  float attn = (segf + 1e-5f)/(segf + segb + 2e-5f);
  float na = 1.f - attn;
  #pragma unroll
  for (int c=0;c<3;c++){
    size_t off = (size_t)(img*3+c)*65536 + p;
    out[O_PRED  + off] = attn*pf[c] + na*pb[c];
    out[O_PREDF + off] = pf[c];
    out[O_PREDB + off] = pb[c];
  }
  size_t oa = (size_t)img*65536 + p;
  out[O_ATTN + oa] = attn;
  out[O_OMA  + oa] = na;
}

// ---------------- launch ----------------
extern "C" void kernel_launch(void* const* d_in, const int* in_sizes, int n_in,
                              void* d_out, int out_size, void* d_ws, size_t ws_size,
                              hipStream_t stream){
  (void)in_sizes; (void)n_in; (void)out_size; (void)ws_size;
  char* ws = (char*)d_ws;
  float* h   = (float*)(ws + WS_H);
  float* tb  = (float*)(ws + WS_T);
  u16*  wdH  = (u16*)(ws + WS_WDH);
  u16*  wdL  = (u16*)(ws + WS_WDL);
  u16*  w2H  = (u16*)(ws + WS_W2H);
  u16*  w2L  = (u16*)(ws + WS_W2L);
  float* w0t = (float*)(ws + WS_W0T);
  float* wft = (float*)(ws + WS_WFT);
  float* par = (float*)(ws + WS_PAR);
  float* out = (float*)d_out;

  k_prep<<<1,256,0,stream>>>((const float*)d_in[4],(const float*)d_in[5],(const float*)d_in[6],(const float*)d_in[7],
                             (const float*)d_in[9],(const float*)d_in[10],(const float*)d_in[11],(const float*)d_in[12],
                             (const float*)d_in[15],(const float*)d_in[16],(const float*)d_in[17],(const float*)d_in[18],
                             (const float*)d_in[20],(const float*)d_in[21],(const float*)d_in[22],(const float*)d_in[23],
                             (const float*)d_in[3],(const float*)d_in[25], par);
  k_wx2<<<86,256,0,stream>>>((const float*)d_in[24],(const float*)d_in[8], wft, w0t);
  k_wxm<<<4320,256,0,stream>>>((const float*)d_in[13],(const float*)d_in[14],(const float*)d_in[19],
                               wdH, wdL, w2H, w2L);

  dim3 g0(16,32,4);   // conv0: 16x8 tiles
  dim3 gm(8,32,4);    // mfma convs: 32x8 tiles
  dim3 gf(16,16,4);   // fin: 16x16 tiles
  for (int dir=0; dir<2; dir++){
    const float* im = (const float*)d_in[dir];
    float* dmask = out + (dir ? O_MASKB : O_MASKF);
    k_conv<9,1,0,0><<<g0,256,0,stream>>>(im, h, w0t, par+S0, par+T0, 6);
    for (int b=0;b<10;b++){
      k_mconv<18,0,0><<<gm,256,0,stream>>>(h, tb, wdH + (size_t)b*73728, wdL + (size_t)b*73728,
                                           par + S1 + b*64, par + T1 + b*64);
      k_mconv<9,1,1><<<gm,256,0,stream>>>(tb, h, w2H + (size_t)b*36864, w2L + (size_t)b*36864,
                                          par + S2 + b*64, par + T2 + b*64);
    }
    k_fin2<<<gf,256,0,stream>>>(h, wft, par, dmask);
  }
  k_blend<<<1024,256,0,stream>>>(out, (const float*)d_in[0], (const float*)d_in[1],
                                 (const float*)d_in[2], par, out);
}